// Round 16
// baseline (141.852 us; speedup 1.0000x reference)
//
#include <hip/hip_runtime.h>

// PointWarping2: Nadaraya-Watson regression of flow1 (at warped sources
// y = xyz1+flow1) onto queries xyz2. B=2,C=3,N1=N2=8192 fp32.
//
// R16 = R15 with the compile fix: __builtin_amdgcn_cvt_pkrtz returns
// __fp16 ext_vector(2), not _Float16 ext_vector(2) -> h2 typedef now __fp16.
// Theory unchanged: v_pk_*_f32 is HALF-rate on gfx950 (busy ~21us vs 17us
// op-floor, all structural changes null R8-R14). fdot2 (f16x2 MAC -> f32)
// is full-rate; BODY processes a SOURCE PAIR per lane: f32 dot (f2 over
// sources), weights pair-packed to f16x2 via cvt_pkrtz, num/den accumulated
// with 4 fdot2 (8 cyc) instead of 4 pk_fma_f32 (16 cyc). Flow stored f16.
// Kept: 16B records, magic-folded Schraudolph exp2 (absmax 0.0586), SGPR
// query consts, split-exchange butterfly, 2-slot prefetch ring.

#define N1S  8192
#define N2S  8192
#define BATCH 2
#define NS   (BATCH * N1S)     // 16384 sources
#define NQ   (BATCH * N2S)     // 16384 queries
#define GUARD 512              // guard elements for unconditional prefetch
#define BLK  256               // 4 waves
#define QB   8                 // queries per block (shared by all 4 waves)
#define CHUNK 2048             // sources per wave
#define ITERS (CHUNK / 128)    // 16 (2 sources per lane per iter)
#define LOG2E 1.4426950408889634f
#define MAGIC 49152.0f         // 1.5*2^15
#define CLAMPS (MAGIC - 120.0f)
#define KBITS 1064990910       // (127<<23) - 362306: rel err +-3.04%

typedef float f2 __attribute__((ext_vector_type(2)));
typedef __fp16 h2 __attribute__((ext_vector_type(2)));   // builtin-native f16x2

__device__ __forceinline__ f2 fma2(f2 a, f2 b, f2 c) {
    return __builtin_elementwise_fma(a, b, c);
}
__device__ __forceinline__ f2 max2(f2 a, f2 b) {
    return __builtin_elementwise_max(a, b);
}
__device__ __forceinline__ f2 bc2(float x) { return (f2){x, x}; }

__device__ __forceinline__ float dot2acc(h2 a, h2 b, float c) {
#if __has_builtin(__builtin_amdgcn_fdot2)
    return __builtin_amdgcn_fdot2(a, b, c, false);   // v_dot2c_f32_f16
#else
    return c + (float)a.x * (float)b.x + (float)a.y * (float)b.y;
#endif
}
__device__ __forceinline__ h2 pkrtz(float a, float b) {
#if __has_builtin(__builtin_amdgcn_cvt_pkrtz)
    return __builtin_amdgcn_cvt_pkrtz(a, b);         // v_cvt_pkrtz_f16_f32
#else
    return (h2){(__fp16)a, (__fp16)b};
#endif
}

__device__ __forceinline__ float rfl(float x) {   // force wave-uniform -> SGPR
    return __builtin_bit_cast(float,
        __builtin_amdgcn_readfirstlane(__builtin_bit_cast(int, x)));
}

__device__ __forceinline__ float read_scale(const void* p) {
    // resol_factor: 1-elem array; Python int -> int32, float -> fp32.
    int iv = *(const int*)p;
    if (iv > -(1 << 23) && iv < (1 << 23)) return (float)iv;
    return *(const float*)p;
}

__device__ __forceinline__ unsigned h16(float v) {        // fp16 bits
    return (unsigned)__builtin_bit_cast(unsigned short, (_Float16)v);
}
__device__ __forceinline__ float h2f(unsigned bits16) {   // fp16 bits -> fp32
    return (float)__builtin_bit_cast(_Float16, (unsigned short)(bits16 & 0xFFFFu));
}

// ---- k1: record per source:
//   u.x = h16(yy)<<16 | h16(yx)   u.y = h16(fx)<<16 | h16(yz)
//   u.z = h16(fz)<<16 | h16(fy)   u.w = fp32 (MAGIC - c1*|y|^2)
__global__ __launch_bounds__(256) void pw2_pack(
    const float* __restrict__ xyz1, const float* __restrict__ flow1,
    const void* __restrict__ resol, uint4* __restrict__ src)
{
    int i = blockIdx.x * 256 + threadIdx.x;
    if (i >= NS) return;
    int b = i >> 13, m = i & (N1S - 1);
    const float scale = read_scale(resol);
    const float c1 = LOG2E / (scale * scale);
    const float* x1b = xyz1  + b * 3 * N1S;
    const float* f1b = flow1 + b * 3 * N1S;
    float fx = f1b[0*N1S+m], fy = f1b[1*N1S+m], fz = f1b[2*N1S+m];
    float yx = x1b[0*N1S+m]+fx, yy = x1b[1*N1S+m]+fy, yz = x1b[2*N1S+m]+fz;
    float yc = MAGIC - c1 * (yx*yx + yy*yy + yz*yz);  // fp32: exact fold
    uint4 u;
    u.x = (h16(yy) << 16) | h16(yx);
    u.y = (h16(fx) << 16) | h16(yz);
    u.z = (h16(fz) << 16) | h16(fy);
    u.w = __builtin_bit_cast(unsigned, yc);
    src[i] = u;
}

// ---- k2: main streaming kernel, source-pair BODY + fdot2 accumulate ----
__global__ __launch_bounds__(BLK) void pw2_main(
    const uint4* __restrict__ src, const float* __restrict__ xyz2,
    const void* __restrict__ resol, float* __restrict__ out)
{
    __shared__ float red[4 * 32];      // [wave][32 reduced values]

    const int t = threadIdx.x;
    const int w = t >> 6;              // wave = source chunk
    const int l = t & 63;

    const int qblk  = blockIdx.x * QB;
    const int b     = qblk >> 13;
    const int nbase = qblk & (N2S - 1);

    const float scale = read_scale(resol);   // INITIAL_RADIUS == 1.0
    const float c1    = LOG2E / (scale * scale);
    const float twoC  = 2.0f * c1;

    const float* x2b = xyz2 + b * 3 * N2S;

    // ---- wave-uniform query constants (8 queries) -> SGPRs ----
    float qx[QB], qy[QB], qz[QB], qc[QB];
#pragma unroll
    for (int q = 0; q < QB; ++q) {
        int n = nbase + q;
        float x = x2b[0*N2S+n], y = x2b[1*N2S+n], z = x2b[2*N2S+n];
        qc[q] = rfl(-c1 * (x*x + y*y + z*z));
        qx[q] = rfl(twoC*x); qy[q] = rfl(twoC*y); qz[q] = rfl(twoC*z);
    }
    const f2 clamp2 = (f2){CLAMPS, CLAMPS};
    const h2 one2   = (h2){(__fp16)1.0f, (__fp16)1.0f};

    // a[c*8+q]: c=0/1/2 numerator xyz, c=3 denominator (f32 accumulators)
    float a[32];
#pragma unroll
    for (int i = 0; i < 32; ++i) a[i] = 0.f;

// BODY: source pair (U0 = s0, U1 = s1). Pairs are (lo=s0, hi=s1) throughout.
#define BODY(U0, U1) do {                                                     \
    f2 yx2 = (f2){h2f((U0).x), h2f((U1).x)};                                  \
    f2 yy2 = (f2){h2f((U0).x >> 16), h2f((U1).x >> 16)};                      \
    f2 yz2 = (f2){h2f((U0).y), h2f((U1).y)};                                  \
    f2 yc2 = (f2){__builtin_bit_cast(float, (U0).w),                          \
                  __builtin_bit_cast(float, (U1).w)};                         \
    h2 fx2 = __builtin_bit_cast(h2,                                           \
        ((U0).y >> 16) | ((U1).y & 0xFFFF0000u));                             \
    h2 fy2 = __builtin_bit_cast(h2,                                           \
        ((U0).z & 0xFFFFu) | ((U1).z << 16));                                 \
    h2 fz2 = __builtin_bit_cast(h2,                                           \
        ((U0).z >> 16) | ((U1).z & 0xFFFF0000u));                             \
    _Pragma("unroll")                                                         \
    for (int q = 0; q < QB; ++q) {                                            \
        f2 arg = fma2(bc2(qx[q]), yx2, yc2);                                  \
        arg = fma2(bc2(qy[q]), yy2, arg);                                     \
        arg = fma2(bc2(qz[q]), yz2, arg);                                     \
        arg = arg + bc2(qc[q]);                                               \
        f2 s = max2(arg, clamp2);                                             \
        float w0 = __builtin_bit_cast(float,                                  \
            (__builtin_bit_cast(int, s.x) << 15) + KBITS);                    \
        float w1 = __builtin_bit_cast(float,                                  \
            (__builtin_bit_cast(int, s.y) << 15) + KBITS);                    \
        h2 w2 = pkrtz(w0, w1);                                                \
        a[0*8+q] = dot2acc(w2, fx2, a[0*8+q]);                                \
        a[1*8+q] = dot2acc(w2, fy2, a[1*8+q]);                                \
        a[2*8+q] = dot2acc(w2, fz2, a[2*8+q]);                                \
        a[3*8+q] = dot2acc(w2, one2, a[3*8+q]);                               \
    }                                                                         \
} while (0)

    // ---- stream 2048 sources (2/lane/iter), 2-slot prefetch ring ----
    int idx = b * N1S + w * CHUNK + l;
    uint4 p0[2], p1[2];
    p0[0] = src[idx];       p1[0] = src[idx + 64];
    p0[1] = src[idx + 128]; p1[1] = src[idx + 192];
#pragma unroll 2
    for (int it = 0; it < ITERS; ++it) {
        uint4 n0 = src[idx + 256];      // guard padding keeps tail legal
        uint4 n1 = src[idx + 320];
        BODY(p0[it & 1], p1[it & 1]);
        p0[it & 1] = n0; p1[it & 1] = n1;
        idx += 128;
    }
#undef BODY

    // ---- split-exchange butterfly: 32 values, offsets 1..16 ----
#pragma unroll
    for (int step = 0; step < 5; ++step) {
        const int off  = 1 << step;
        const int half = 16 >> step;
        const bool hi  = (l & off) != 0;
#pragma unroll
        for (int k = 0; k < half; ++k) {
            float give = hi ? a[k] : a[k + half];
            float recv = __shfl_xor(give, off, 64);
            float keep = hi ? a[k + half] : a[k];
            a[k] = keep + recv;
        }
    }
    a[0] += __shfl_xor(a[0], 32, 64);   // merge the two 32-lane halves
    if (l < 32) red[w * 32 + (__brev((unsigned)l) >> 27)] = a[0];
    __syncthreads();

    // ---- combine 4 chunk partials per query, normalize, write ----
    if (t < QB) {
        int q = t;
        float nx = 0.f, ny = 0.f, nz = 0.f, dn = 0.f;
#pragma unroll
        for (int ww = 0; ww < 4; ++ww) {
            const float* r = red + ww * 32;
            nx += r[0*8 + q];
            ny += r[1*8 + q];
            nz += r[2*8 + q];
            dn += r[3*8 + q];
        }
        float inv = 1.0f / dn;
        int n = nbase + q;
        out[b*3*N2S + 0*N2S + n] = x2b[0*N2S+n] - nx*inv;
        out[b*3*N2S + 1*N2S + n] = x2b[1*N2S+n] - ny*inv;
        out[b*3*N2S + 2*N2S + n] = x2b[2*N2S+n] - nz*inv;
    }
}

extern "C" void kernel_launch(void* const* d_in, const int* in_sizes, int n_in,
                              void* d_out, int out_size, void* d_ws, size_t ws_size,
                              hipStream_t stream) {
    const float* xyz1  = (const float*)d_in[0];
    const float* xyz2  = (const float*)d_in[1];
    const float* flow1 = (const float*)d_in[2];
    const void*  resol = d_in[3];
    float* out = (float*)d_out;

    uint4* src = (uint4*)d_ws;             // (NS+GUARD) uint4

    pw2_pack<<<NS / 256, 256, 0, stream>>>(xyz1, flow1, resol, src);
    pw2_main<<<NQ / QB, BLK, 0, stream>>>(src, xyz2, resol, out);
}

// Round 17
// 88.689 us; speedup vs baseline: 1.5994x; 1.5994x over previous
//
#include <hip/hip_runtime.h>

// PointWarping2: Nadaraya-Watson regression of flow1 (at warped sources
// y = xyz1+flow1) onto queries xyz2. B=2,C=3,N1=N2=8192 fp32.
//
// R17 = exact revert to R12, the measured optimum of this session.
// Final model (R7-R16 evidence):
//   total ~= 40us harness ws-poison fill + ~10us launch/graph + 2us pack
//          + main(21us VALU busy-floor + ~16us constant ramp) ~= 89us.
//   * busy 21us == fp32 issue floor for ~6.5 instr/pair (pk f32 is
//     HALF-rate on gfx950: packed == scalar; R9 scalar and R12 pk tie).
//   * the ~16us idle is CONSTANT across 6 structural variants (streams/
//     DMA-LDS, 4-8 waves/SIMD, 32/16/0 barriers, 3.6x instr count) - not
//     coverage-dependent.
//   * fdot2 (R16): not full-rate -> 3.6x busy regression. MFMA rejected on
//     arithmetic (K=8 dot too small; exp+accum stay VALU).
// Record: u={h16(yy,yx), bf16(fx)|h16(yz), bf16(fz,fy), f32 MAGIC-c1|y|^2};
// Schraudolph exp2 via magic-fold (absmax 0.0586 < 0.0862 threshold);
// SGPR wave-uniform query consts; depth-6 guarded prefetch;
// split-exchange butterfly reduction.

#define N1S  8192
#define N2S  8192
#define BATCH 2
#define NS   (BATCH * N1S)     // 16384 sources
#define NQ   (BATCH * N2S)     // 16384 queries
#define GUARD 512              // guard elements for unconditional prefetch
#define BLK  256               // 4 waves
#define QB   8                 // queries per block (shared by all 4 waves)
#define QP   4                 // f2 query-pairs per wave
#define CHUNK 2048             // sources per wave
#define ITERS (CHUNK / 64)     // 32
#define DEPTH 6                // software-pipeline depth
#define LOG2E 1.4426950408889634f
#define MAGIC 49152.0f         // 1.5*2^15
#define CLAMPS (MAGIC - 120.0f)
#define KBITS 1064990910       // (127<<23) - 362306: rel err +-3.04%

typedef float f2 __attribute__((ext_vector_type(2)));

__device__ __forceinline__ f2 fma2(f2 a, f2 b, f2 c) {
    return __builtin_elementwise_fma(a, b, c);
}
__device__ __forceinline__ f2 max2(f2 a, f2 b) {
    return __builtin_elementwise_max(a, b);
}

__device__ __forceinline__ float rfl(float x) {   // force wave-uniform -> SGPR
    return __builtin_bit_cast(float,
        __builtin_amdgcn_readfirstlane(__builtin_bit_cast(int, x)));
}

__device__ __forceinline__ float read_scale(const void* p) {
    // resol_factor: 1-elem array; Python int -> int32, float -> fp32.
    int iv = *(const int*)p;
    if (iv > -(1 << 23) && iv < (1 << 23)) return (float)iv;
    return *(const float*)p;
}

__device__ __forceinline__ unsigned bf16_rne(float v) {   // round-nearest-even
    unsigned u = __builtin_bit_cast(unsigned, v);
    return (u + 0x7FFFu + ((u >> 16) & 1u)) >> 16;
}

__device__ __forceinline__ unsigned h16(float v) {        // fp16 bits
    return (unsigned)__builtin_bit_cast(unsigned short, (_Float16)v);
}

__device__ __forceinline__ float h2f(unsigned bits16) {   // fp16 bits -> fp32
    return (float)__builtin_bit_cast(_Float16, (unsigned short)(bits16 & 0xFFFFu));
}

// ---- k1: pack one uint4 record per source ----
__global__ __launch_bounds__(256) void pw2_pack(
    const float* __restrict__ xyz1, const float* __restrict__ flow1,
    const void* __restrict__ resol, uint4* __restrict__ src)
{
    int i = blockIdx.x * 256 + threadIdx.x;
    if (i >= NS) return;
    int b = i >> 13, m = i & (N1S - 1);
    const float scale = read_scale(resol);
    const float c1 = LOG2E / (scale * scale);
    const float* x1b = xyz1  + b * 3 * N1S;
    const float* f1b = flow1 + b * 3 * N1S;
    float fx = f1b[0*N1S+m], fy = f1b[1*N1S+m], fz = f1b[2*N1S+m];
    float yx = x1b[0*N1S+m]+fx, yy = x1b[1*N1S+m]+fy, yz = x1b[2*N1S+m]+fz;
    float yc = MAGIC - c1 * (yx*yx + yy*yy + yz*yz);  // fp32: exact fold
    uint4 u;
    u.x = (h16(yy) << 16) | h16(yx);
    u.y = (bf16_rne(fx) << 16) | h16(yz);
    u.z = (bf16_rne(fz) << 16) | bf16_rne(fy);
    u.w = __builtin_bit_cast(unsigned, yc);
    src[i] = u;
}

// ---- k2: main streaming kernel ----
__global__ __launch_bounds__(BLK) void pw2_main(
    const uint4* __restrict__ src, const float* __restrict__ xyz2,
    const void* __restrict__ resol, float* __restrict__ out)
{
    __shared__ float red[4 * 32];      // [wave][32 reduced values]

    const int t = threadIdx.x;
    const int w = t >> 6;              // wave = source chunk
    const int l = t & 63;

    const int qblk  = blockIdx.x * QB;
    const int b     = qblk >> 13;
    const int nbase = qblk & (N2S - 1);

    const float scale = read_scale(resol);   // INITIAL_RADIUS == 1.0
    const float c1    = LOG2E / (scale * scale);
    const float twoC  = 2.0f * c1;

    const float* x2b = xyz2 + b * 3 * N2S;

    // ---- wave-uniform query constants (8 queries, f2 pairs) -> SGPRs ----
    f2 qx[QP], qy[QP], qz[QP], qc[QP];
#pragma unroll
    for (int jp = 0; jp < QP; ++jp) {
        int n0 = nbase + 2 * jp;
        float x0 = x2b[0*N2S+n0],   y0 = x2b[1*N2S+n0],   z0 = x2b[2*N2S+n0];
        float x1 = x2b[0*N2S+n0+1], y1 = x2b[1*N2S+n0+1], z1 = x2b[2*N2S+n0+1];
        qc[jp] = (f2){rfl(-c1 * (x0*x0 + y0*y0 + z0*z0)),
                      rfl(-c1 * (x1*x1 + y1*y1 + z1*z1))};
        qx[jp] = (f2){rfl(twoC*x0), rfl(twoC*x1)};
        qy[jp] = (f2){rfl(twoC*y0), rfl(twoC*y1)};
        qz[jp] = (f2){rfl(twoC*z0), rfl(twoC*z1)};
    }
    const f2 clamp2 = (f2){CLAMPS, CLAMPS};

    // acc.v2[c*QP+jp]: c=0/1/2 numerator xyz, c=3 denominator; 32 floats
    union Acc { f2 v2[16]; float v1[32]; } acc;
#pragma unroll
    for (int i = 0; i < 16; ++i) acc.v2[i] = (f2){0.f, 0.f};

#define BODY(U) do {                                                          \
    float vyx = h2f((U).x & 0xFFFFu);                                         \
    float vyy = h2f((U).x >> 16);                                             \
    float vyz = h2f((U).y & 0xFFFFu);                                         \
    float ffx = __builtin_bit_cast(float, (U).y & 0xFFFF0000u);               \
    float ffy = __builtin_bit_cast(float, (U).z << 16);                       \
    float ffz = __builtin_bit_cast(float, (U).z & 0xFFFF0000u);               \
    float vyc = __builtin_bit_cast(float, (U).w);                             \
    f2 yaw = (f2){vyc, vyc};                                                  \
    f2 yax = (f2){vyx, vyx}, yay = (f2){vyy, vyy}, yaz = (f2){vyz, vyz};      \
    f2 fax = (f2){ffx, ffx}, fay = (f2){ffy, ffy}, faz = (f2){ffz, ffz};      \
    _Pragma("unroll")                                                         \
    for (int jp = 0; jp < QP; ++jp) {                                         \
        f2 arg = qc[jp] + yaw;                                                \
        arg = fma2(qx[jp], yax, arg);                                         \
        arg = fma2(qy[jp], yay, arg);                                         \
        arg = fma2(qz[jp], yaz, arg);                                         \
        f2 s = max2(arg, clamp2);                                             \
        f2 wgt = (f2){                                                        \
            __builtin_bit_cast(float,                                         \
                (__builtin_bit_cast(int, s.x) << 15) + KBITS),                \
            __builtin_bit_cast(float,                                         \
                (__builtin_bit_cast(int, s.y) << 15) + KBITS)};               \
        acc.v2[0*QP+jp] = fma2(wgt, fax, acc.v2[0*QP+jp]);                    \
        acc.v2[1*QP+jp] = fma2(wgt, fay, acc.v2[1*QP+jp]);                    \
        acc.v2[2*QP+jp] = fma2(wgt, faz, acc.v2[2*QP+jp]);                    \
        acc.v2[3*QP+jp] = acc.v2[3*QP+jp] + wgt;                              \
    }                                                                         \
} while (0)

    // ---- depth-6 branch-free pipeline over 2048 sources (guarded tail) ----
    int idx = b * N1S + w * CHUNK + l;
    uint4 ub[DEPTH];
#pragma unroll
    for (int p = 0; p < DEPTH; ++p) ub[p] = src[idx + p * 64];
#pragma unroll 6
    for (int it = 0; it < ITERS; ++it) {
        uint4 un = src[idx + DEPTH * 64];   // guard padding: always legal
        BODY(ub[it % DEPTH]);
        ub[it % DEPTH] = un;
        idx += 64;
    }
#undef BODY

    // ---- split-exchange butterfly: 32 values, offsets 1..16 ----
#pragma unroll
    for (int step = 0; step < 5; ++step) {
        const int off  = 1 << step;
        const int half = 16 >> step;
        const bool hi  = (l & off) != 0;
#pragma unroll
        for (int k = 0; k < half; ++k) {
            float give = hi ? acc.v1[k] : acc.v1[k + half];
            float recv = __shfl_xor(give, off, 64);
            float keep = hi ? acc.v1[k + half] : acc.v1[k];
            acc.v1[k] = keep + recv;
        }
    }
    acc.v1[0] += __shfl_xor(acc.v1[0], 32, 64);  // merge the two 32-lane halves
    if (l < 32) red[w * 32 + (__brev((unsigned)l) >> 27)] = acc.v1[0];
    __syncthreads();

    // ---- combine 4 chunk partials per query, normalize, write ----
    if (t < QB) {
        int q = t;
        // flat value index for component c of query q: 2*(c*QP + q/2) + (q&1)
        float nx = 0.f, ny = 0.f, nz = 0.f, dn = 0.f;
#pragma unroll
        for (int ww = 0; ww < 4; ++ww) {
            const float* r = red + ww * 32;
            nx += r[2*(0*QP + (q>>1)) + (q&1)];
            ny += r[2*(1*QP + (q>>1)) + (q&1)];
            nz += r[2*(2*QP + (q>>1)) + (q&1)];
            dn += r[2*(3*QP + (q>>1)) + (q&1)];
        }
        float inv = 1.0f / dn;
        int n = nbase + q;
        out[b*3*N2S + 0*N2S + n] = x2b[0*N2S+n] - nx*inv;
        out[b*3*N2S + 1*N2S + n] = x2b[1*N2S+n] - ny*inv;
        out[b*3*N2S + 2*N2S + n] = x2b[2*N2S+n] - nz*inv;
    }
}

extern "C" void kernel_launch(void* const* d_in, const int* in_sizes, int n_in,
                              void* d_out, int out_size, void* d_ws, size_t ws_size,
                              hipStream_t stream) {
    const float* xyz1  = (const float*)d_in[0];
    const float* xyz2  = (const float*)d_in[1];
    const float* flow1 = (const float*)d_in[2];
    const void*  resol = d_in[3];
    float* out = (float*)d_out;

    uint4* src = (uint4*)d_ws;             // (NS+GUARD) uint4 = ~270 KB

    pw2_pack<<<NS / 256, 256, 0, stream>>>(xyz1, flow1, resol, src);
    pw2_main<<<NQ / QB, BLK, 0, stream>>>(src, xyz2, resol, out);
}